// Round 3
// baseline (9298.995 us; speedup 1.0000x reference)
//
#include <hip/hip_runtime.h>
#include <cstddef>

#define NT 512

namespace {
constexpr int NWIN = 72;     // tokens per window
constexpr int DIM  = 192;
constexpr int HD   = 32;     // head dim
constexpr float QSCALE = 0.17677669529663687f;  // 32^-0.5

// LDS layout (float offsets)
constexpr int Q2_OFF   = 0;                   // [72][64]  q, 2 heads
constexpr int K2T_OFF  = Q2_OFF  + 72 * 64;   // [64][73]  k transposed (stride 73 -> conflict-free)
constexpr int V2_OFF   = K2T_OFF + 64 * 73;   // [72][64]  v, 2 heads
constexpr int PO_OFF   = V2_OFF  + 72 * 64;   // [72][192] concat attention output
constexpr int UN_OFF   = PO_OFF  + 72 * 192;  // union: {W [32][192] + xchunk [72][32]} | S0,S1 [72][76]
constexpr int UNX_REL  = 32 * 192;            // x-chunk offset inside union (6144)
constexpr int S_STRIDE = 76;
constexpr int S1_REL   = 72 * S_STRIDE;
constexpr int LDS_FLOATS = UN_OFF + 2 * S1_REL;   // 38656 floats = 154,624 B (<160 KiB)
}

__device__ __forceinline__ float bias_val(const float* __restrict__ btab,
                                          int a, int b, int h, int w31, int tlat) {
  // bias = table[pos[((a*72+b)*60 + w/31) % 5184], w % 31, h]
  int Q  = a * NWIN + b;
  int P  = (Q * 60 + w31) % 5184;
  int p1 = P / NWIN;
  int p2 = P - p1 * NWIN;
  int i1 = p1 / 12, j1 = p1 - i1 * 12;
  int i2 = p2 / 12, j2 = p2 - i2 * 12;
  int row = (i1 + 6 * i2) * 23 + (j1 - j2 + 11);
  return btab[(row * 31 + tlat) * 6 + h];
}

// LDS-bound occupancy is 1 block/CU (154 KB of 160 KB) = 2 waves/SIMD.
// So request exactly 2 waves/EU -> 256-VGPR budget. Do NOT pass a 2nd
// launch_bounds arg: it imposed a 128-VGPR cap (rounds 1-2) and the
// resulting scratch spills generated ~6 GB/launch of HBM traffic.
__global__ __launch_bounds__(NT) __attribute__((amdgpu_waves_per_eu(2)))
void earth_attn_kernel(const float* __restrict__ x,    const float* __restrict__ mask,
                       const float* __restrict__ wqkv, const float* __restrict__ bqkv,
                       const float* __restrict__ wout, const float* __restrict__ bout,
                       const float* __restrict__ btab, float* __restrict__ out)
{
  extern __shared__ float lds[];
  float* q2  = lds + Q2_OFF;
  float* k2T = lds + K2T_OFF;
  float* v2  = lds + V2_OFF;
  float* po  = lds + PO_OFF;
  float* un  = lds + UN_OFF;
  float* unx = un + UNX_REL;

  const int w   = blockIdx.x;
  const int tid = threadIdx.x;
  const int tx  = tid & 63;   // lane within wave
  const int ty  = tid >> 6;   // wave id 0..7 (uniform per wave)

  const int mrow = w % 30;
  const int tlat = w % 31;
  const int w31  = w / 31;

  const float* xw    = x + (size_t)w * (NWIN * DIM);
  const float* maskw = mask + (size_t)mrow * (NWIN * NWIN);

  for (int pass = 0; pass < 3; ++pass) {
    const int h0 = pass * 2;

    // ---------- GEMM A: qkv (heads h0, h0+1): rows rr*8+ty, cols cc*64+tx ----------
    float a0[9], a1[9], a2[9];
    #pragma unroll
    for (int rr = 0; rr < 9; ++rr) { a0[rr] = 0.f; a1[rr] = 0.f; a2[rr] = 0.f; }

    for (int k0 = 0; k0 < DIM; k0 += 32) {
      __syncthreads();  // protect union buffer (prev pass S / prev stage W)
      // stage W chunk [32][192] (column-remapped to heads h0,h0+1), float4
      #pragma unroll
      for (int i = 0; i < 3; ++i) {
        int e4 = tid + i * NT;          // 0..1535
        int kk = e4 / 48;
        int c4 = e4 - kk * 48;
        int blk = c4 >> 4;              // 0..2 (q/k/v)
        int wi  = c4 & 15;              // float4 within 64-wide slice
        float4 t = *(const float4*)(wqkv + (size_t)(k0 + kk) * 576 + blk * DIM + h0 * HD + wi * 4);
        *(float4*)(un + kk * 192 + blk * 64 + wi * 4) = t;
      }
      // stage x chunk [72][32], float4 (576 float4s)
      {
        int e = tid;                    // first 512
        int r = e >> 3, c4 = e & 7;
        *(float4*)(unx + r * 32 + c4 * 4) = *(const float4*)(xw + r * DIM + k0 + c4 * 4);
        e = tid + NT;
        if (e < 576) {
          r = e >> 3; c4 = e & 7;
          *(float4*)(unx + r * 32 + c4 * 4) = *(const float4*)(xw + r * DIM + k0 + c4 * 4);
        }
      }
      __syncthreads();
      #pragma unroll
      for (int kk0 = 0; kk0 < 32; kk0 += 4) {
        float wv0[4], wv1[4], wv2[4];
        #pragma unroll
        for (int j = 0; j < 4; ++j) {
          wv0[j] = un[(kk0 + j) * 192 + tx];
          wv1[j] = un[(kk0 + j) * 192 + 64 + tx];
          wv2[j] = un[(kk0 + j) * 192 + 128 + tx];
        }
        #pragma unroll
        for (int rr = 0; rr < 9; ++rr) {
          float4 xa = *(const float4*)(unx + (rr * 8 + ty) * 32 + kk0);  // wave-broadcast
          a0[rr] = fmaf(xa.x, wv0[0], a0[rr]);
          a0[rr] = fmaf(xa.y, wv0[1], a0[rr]);
          a0[rr] = fmaf(xa.z, wv0[2], a0[rr]);
          a0[rr] = fmaf(xa.w, wv0[3], a0[rr]);
          a1[rr] = fmaf(xa.x, wv1[0], a1[rr]);
          a1[rr] = fmaf(xa.y, wv1[1], a1[rr]);
          a1[rr] = fmaf(xa.z, wv1[2], a1[rr]);
          a1[rr] = fmaf(xa.w, wv1[3], a1[rr]);
          a2[rr] = fmaf(xa.x, wv2[0], a2[rr]);
          a2[rr] = fmaf(xa.y, wv2[1], a2[rr]);
          a2[rr] = fmaf(xa.z, wv2[2], a2[rr]);
          a2[rr] = fmaf(xa.w, wv2[3], a2[rr]);
        }
      }
    }

    {  // epilogue: +bias, scale q, store to LDS
      float bq = bqkv[h0 * HD + tx];
      float bk = bqkv[DIM + h0 * HD + tx];
      float bv = bqkv[2 * DIM + h0 * HD + tx];
      #pragma unroll
      for (int rr = 0; rr < 9; ++rr) {
        int r = rr * 8 + ty;
        q2[r * 64 + tx]  = (a0[rr] + bq) * QSCALE;
        k2T[tx * 73 + r] = a1[rr] + bk;     // transposed store, stride 73
        v2[r * 64 + tx]  = a2[rr] + bv;
      }
    }
    __syncthreads();

    // ---------- S = q k^T, both heads; cols b = tx and 64+tx (tx<8) ----------
    float s0[9][2], s1[9][2];
    #pragma unroll
    for (int rr = 0; rr < 9; ++rr) { s0[rr][0]=0.f; s0[rr][1]=0.f; s1[rr][0]=0.f; s1[rr][1]=0.f; }
    #pragma unroll
    for (int hh = 0; hh < 2; ++hh) {
      const int off = hh * HD;
      #pragma unroll
      for (int kk0 = 0; kk0 < HD; kk0 += 4) {
        float kva[4], kvb[4];
        #pragma unroll
        for (int j = 0; j < 4; ++j) {
          kva[j] = k2T[(off + kk0 + j) * 73 + tx];
          kvb[j] = k2T[(off + kk0 + j) * 73 + 64 + tx];  // junk for tx>=8 (discarded, in-LDS)
        }
        #pragma unroll
        for (int rr = 0; rr < 9; ++rr) {
          float4 q4 = *(const float4*)(q2 + (rr * 8 + ty) * 64 + off + kk0);  // wave-broadcast
          float da = q4.x*kva[0] + q4.y*kva[1] + q4.z*kva[2] + q4.w*kva[3];
          float db = q4.x*kvb[0] + q4.y*kvb[1] + q4.z*kvb[2] + q4.w*kvb[3];
          if (hh == 0) { s0[rr][0] += da; s0[rr][1] += db; }
          else         { s1[rr][0] += da; s1[rr][1] += db; }
        }
      }
    }

    // ---------- bias + mask + softmax (row lives in one wave -> shfl reduce) ----------
    float* S0 = un;
    float* S1 = un + S1_REL;
    #pragma unroll
    for (int rr = 0; rr < 9; ++rr) {
      const int a = rr * 8 + ty;
      const float m0  = maskw[a * NWIN + tx];
      const float m1v = (tx < 8) ? maskw[a * NWIN + 64 + tx] : 0.f;
      #pragma unroll
      for (int hh = 0; hh < 2; ++hh) {
        const int h = h0 + hh;
        float v0 = (hh ? s1[rr][0] : s0[rr][0]) + bias_val(btab, a, tx, h, w31, tlat) + m0;
        float v1 = -1e30f;
        if (tx < 8)
          v1 = (hh ? s1[rr][1] : s0[rr][1]) + bias_val(btab, a, 64 + tx, h, w31, tlat) + m1v;
        float mx = fmaxf(v0, v1);
        #pragma unroll
        for (int o = 32; o > 0; o >>= 1) mx = fmaxf(mx, __shfl_xor(mx, o));
        float e0 = __expf(v0 - mx);
        float e1 = (tx < 8) ? __expf(v1 - mx) : 0.f;
        float sm = e0 + e1;
        #pragma unroll
        for (int o = 32; o > 0; o >>= 1) sm += __shfl_xor(sm, o);
        float inv = 1.0f / sm;
        float* Sh = hh ? S1 : S0;
        Sh[a * S_STRIDE + tx] = e0 * inv;
        if (tx < 8) Sh[a * S_STRIDE + 64 + tx] = e1 * inv;
      }
    }

    // ---------- PV: out col = pass*64 + tx (head = tx/32). Same-wave S dep: no barrier ----------
    {
      const float* Sh = (tx < 32) ? S0 : S1;
      float o[9];
      #pragma unroll
      for (int rr = 0; rr < 9; ++rr) o[rr] = 0.f;
      for (int b0 = 0; b0 < NWIN; b0 += 4) {
        float vv[4];
        #pragma unroll
        for (int j = 0; j < 4; ++j) vv[j] = v2[(b0 + j) * 64 + tx];
        #pragma unroll
        for (int rr = 0; rr < 9; ++rr) {
          float4 p4 = *(const float4*)(Sh + (rr * 8 + ty) * S_STRIDE + b0);
          o[rr] += p4.x*vv[0] + p4.y*vv[1] + p4.z*vv[2] + p4.w*vv[3];
        }
      }
      #pragma unroll
      for (int rr = 0; rr < 9; ++rr)
        po[(rr * 8 + ty) * DIM + pass * 64 + tx] = o[rr];
    }
  }  // pass

  // ---------- out projection: y = po @ w_out + b_out ----------
  float c0[9], c1[9], c2[9];
  #pragma unroll
  for (int rr = 0; rr < 9; ++rr) { c0[rr] = 0.f; c1[rr] = 0.f; c2[rr] = 0.f; }
  for (int k0 = 0; k0 < DIM; k0 += 32) {
    __syncthreads();  // protect union (last used as S by PV)
    #pragma unroll
    for (int i = 0; i < 3; ++i) {
      int e4 = tid + i * NT;            // 0..1535
      int kk = e4 / 48;
      int c4 = e4 - kk * 48;
      float4 t = *(const float4*)(wout + (size_t)(k0 + kk) * DIM + c4 * 4);
      *(float4*)(un + kk * 192 + c4 * 4) = t;
    }
    __syncthreads();
    #pragma unroll
    for (int kk0 = 0; kk0 < 32; kk0 += 4) {
      float wv0[4], wv1[4], wv2[4];
      #pragma unroll
      for (int j = 0; j < 4; ++j) {
        wv0[j] = un[(kk0 + j) * 192 + tx];
        wv1[j] = un[(kk0 + j) * 192 + 64 + tx];
        wv2[j] = un[(kk0 + j) * 192 + 128 + tx];
      }
      #pragma unroll
      for (int rr = 0; rr < 9; ++rr) {
        float4 pa = *(const float4*)(po + (rr * 8 + ty) * DIM + k0 + kk0);  // wave-broadcast
        c0[rr] = fmaf(pa.x, wv0[0], c0[rr]);
        c0[rr] = fmaf(pa.y, wv0[1], c0[rr]);
        c0[rr] = fmaf(pa.z, wv0[2], c0[rr]);
        c0[rr] = fmaf(pa.w, wv0[3], c0[rr]);
        c1[rr] = fmaf(pa.x, wv1[0], c1[rr]);
        c1[rr] = fmaf(pa.y, wv1[1], c1[rr]);
        c1[rr] = fmaf(pa.z, wv1[2], c1[rr]);
        c1[rr] = fmaf(pa.w, wv1[3], c1[rr]);
        c2[rr] = fmaf(pa.x, wv2[0], c2[rr]);
        c2[rr] = fmaf(pa.y, wv2[1], c2[rr]);
        c2[rr] = fmaf(pa.z, wv2[2], c2[rr]);
        c2[rr] = fmaf(pa.w, wv2[3], c2[rr]);
      }
    }
  }
  {
    const float b0v = bout[tx];
    const float b1v = bout[64 + tx];
    const float b2v = bout[128 + tx];
    float* ow = out + (size_t)w * (NWIN * DIM);
    #pragma unroll
    for (int rr = 0; rr < 9; ++rr) {
      int r = rr * 8 + ty;
      ow[r * DIM + tx]       = c0[rr] + b0v;
      ow[r * DIM + 64 + tx]  = c1[rr] + b1v;
      ow[r * DIM + 128 + tx] = c2[rr] + b2v;
    }
  }
}

extern "C" void kernel_launch(void* const* d_in, const int* in_sizes, int n_in,
                              void* d_out, int out_size, void* d_ws, size_t ws_size,
                              hipStream_t stream) {
  const float* x    = (const float*)d_in[0];
  const float* mask = (const float*)d_in[1];
  const float* wqkv = (const float*)d_in[2];
  const float* bqkv = (const float*)d_in[3];
  const float* wout = (const float*)d_in[4];
  const float* bout = (const float*)d_in[5];
  const float* btab = (const float*)d_in[6];
  float* out = (float*)d_out;

  const int nwindows = in_sizes[0] / (NWIN * DIM);   // 1860
  const size_t ldsB = (size_t)LDS_FLOATS * sizeof(float);  // 154,624 B

  (void)hipFuncSetAttribute((const void*)earth_attn_kernel,
                            hipFuncAttributeMaxDynamicSharedMemorySize, (int)ldsB);

  hipLaunchKernelGGL(earth_attn_kernel, dim3(nwindows), dim3(NT), ldsB, stream,
                     x, mask, wqkv, bqkv, wout, bout, btab, out);
}

// Round 4
// 1641.368 us; speedup vs baseline: 5.6654x; 5.6654x over previous
//
#include <hip/hip_runtime.h>
#include <cstddef>

#define NT 512

namespace {
constexpr int NWIN = 72;     // tokens per window
constexpr int DIM  = 192;
constexpr int HD   = 32;     // head dim
constexpr float QSCALE = 0.17677669529663687f;  // 32^-0.5

// LDS layout (float offsets)
constexpr int Q2_OFF   = 0;                   // [72][64]  q, 2 heads
constexpr int K2T_OFF  = Q2_OFF  + 72 * 64;   // [64][73]  k transposed (stride 73 -> conflict-free)
constexpr int V2_OFF   = K2T_OFF + 64 * 73;   // [72][64]  v, 2 heads
constexpr int PO_OFF   = V2_OFF  + 72 * 64;   // [72][192] concat attention output
constexpr int UN_OFF   = PO_OFF  + 72 * 192;  // union: {W [32][192] + xchunk [72][32]} | S0,S1 [72][76]
constexpr int UNX_REL  = 32 * 192;            // x-chunk offset inside union (6144)
constexpr int S_STRIDE = 76;
constexpr int S1_REL   = 72 * S_STRIDE;
constexpr int LDS_FLOATS = UN_OFF + 2 * S1_REL;   // 38656 floats = 154,624 B (<160 KiB)
}

__device__ __forceinline__ float bias_val(const float* __restrict__ btab,
                                          int a, int b, int h, int w31, int tlat) {
  // bias = table[pos[((a*72+b)*60 + w/31) % 5184], w % 31, h]
  int Q  = a * NWIN + b;
  int P  = (Q * 60 + w31) % 5184;
  int p1 = P / NWIN;
  int p2 = P - p1 * NWIN;
  int i1 = p1 / 12, j1 = p1 - i1 * 12;
  int i2 = p2 / 12, j2 = p2 - i2 * 12;
  int row = (i1 + 6 * i2) * 23 + (j1 - j2 + 11);
  return btab[(row * 31 + tlat) * 6 + h];
}

// NOTE: dynamic LDS (154 KB -> 1 block/CU) is invisible to the compiler
// (LDS_Block_Size=0 in rocprof), so it budgets VGPRs for high occupancy
// (128 cap). Rounds 1-3 spilled ~6 GB/launch of scratch because full
// unrolls hoisted 96+ LDS reads. Fix: cap inner-loop unroll at 2 so the
// live set fits in 128 VGPRs.
__global__ __launch_bounds__(NT) __attribute__((amdgpu_waves_per_eu(2, 2)))
void earth_attn_kernel(const float* __restrict__ x,    const float* __restrict__ mask,
                       const float* __restrict__ wqkv, const float* __restrict__ bqkv,
                       const float* __restrict__ wout, const float* __restrict__ bout,
                       const float* __restrict__ btab, float* __restrict__ out)
{
  extern __shared__ float lds[];
  float* q2  = lds + Q2_OFF;
  float* k2T = lds + K2T_OFF;
  float* v2  = lds + V2_OFF;
  float* po  = lds + PO_OFF;
  float* un  = lds + UN_OFF;
  float* unx = un + UNX_REL;

  const int w   = blockIdx.x;
  const int tid = threadIdx.x;
  const int tx  = tid & 63;   // lane within wave
  const int ty  = tid >> 6;   // wave id 0..7 (uniform per wave)

  const int mrow = w % 30;
  const int tlat = w % 31;
  const int w31  = w / 31;

  const float* xw    = x + (size_t)w * (NWIN * DIM);
  const float* maskw = mask + (size_t)mrow * (NWIN * NWIN);

  for (int pass = 0; pass < 3; ++pass) {
    const int h0 = pass * 2;

    // ---------- GEMM A: qkv (heads h0, h0+1): rows rr*8+ty, cols cc*64+tx ----------
    float a0[9], a1[9], a2[9];
    #pragma unroll
    for (int rr = 0; rr < 9; ++rr) { a0[rr] = 0.f; a1[rr] = 0.f; a2[rr] = 0.f; }

    for (int k0 = 0; k0 < DIM; k0 += 32) {
      __syncthreads();  // protect union buffer (prev pass S / prev stage W)
      // stage W chunk [32][192] (column-remapped to heads h0,h0+1), float4
      #pragma unroll
      for (int i = 0; i < 3; ++i) {
        int e4 = tid + i * NT;          // 0..1535
        int kk = e4 / 48;
        int c4 = e4 - kk * 48;
        int blk = c4 >> 4;              // 0..2 (q/k/v)
        int wi  = c4 & 15;              // float4 within 64-wide slice
        float4 t = *(const float4*)(wqkv + (size_t)(k0 + kk) * 576 + blk * DIM + h0 * HD + wi * 4);
        *(float4*)(un + kk * 192 + blk * 64 + wi * 4) = t;
      }
      // stage x chunk [72][32], float4 (576 float4s)
      {
        int e = tid;                    // first 512
        int r = e >> 3, c4 = e & 7;
        *(float4*)(unx + r * 32 + c4 * 4) = *(const float4*)(xw + r * DIM + k0 + c4 * 4);
        e = tid + NT;
        if (e < 576) {
          r = e >> 3; c4 = e & 7;
          *(float4*)(unx + r * 32 + c4 * 4) = *(const float4*)(xw + r * DIM + k0 + c4 * 4);
        }
      }
      __syncthreads();
      #pragma unroll 2   // cap: full unroll hoists 96 LDS reads -> scratch spill
      for (int kk0 = 0; kk0 < 32; kk0 += 4) {
        float wv0[4], wv1[4], wv2[4];
        #pragma unroll
        for (int j = 0; j < 4; ++j) {
          wv0[j] = un[(kk0 + j) * 192 + tx];
          wv1[j] = un[(kk0 + j) * 192 + 64 + tx];
          wv2[j] = un[(kk0 + j) * 192 + 128 + tx];
        }
        #pragma unroll
        for (int rr = 0; rr < 9; ++rr) {
          float4 xa = *(const float4*)(unx + (rr * 8 + ty) * 32 + kk0);  // wave-broadcast
          a0[rr] = fmaf(xa.x, wv0[0], a0[rr]);
          a0[rr] = fmaf(xa.y, wv0[1], a0[rr]);
          a0[rr] = fmaf(xa.z, wv0[2], a0[rr]);
          a0[rr] = fmaf(xa.w, wv0[3], a0[rr]);
          a1[rr] = fmaf(xa.x, wv1[0], a1[rr]);
          a1[rr] = fmaf(xa.y, wv1[1], a1[rr]);
          a1[rr] = fmaf(xa.z, wv1[2], a1[rr]);
          a1[rr] = fmaf(xa.w, wv1[3], a1[rr]);
          a2[rr] = fmaf(xa.x, wv2[0], a2[rr]);
          a2[rr] = fmaf(xa.y, wv2[1], a2[rr]);
          a2[rr] = fmaf(xa.z, wv2[2], a2[rr]);
          a2[rr] = fmaf(xa.w, wv2[3], a2[rr]);
        }
      }
    }

    {  // epilogue: +bias, scale q, store to LDS
      float bq = bqkv[h0 * HD + tx];
      float bk = bqkv[DIM + h0 * HD + tx];
      float bv = bqkv[2 * DIM + h0 * HD + tx];
      #pragma unroll
      for (int rr = 0; rr < 9; ++rr) {
        int r = rr * 8 + ty;
        q2[r * 64 + tx]  = (a0[rr] + bq) * QSCALE;
        k2T[tx * 73 + r] = a1[rr] + bk;     // transposed store, stride 73
        v2[r * 64 + tx]  = a2[rr] + bv;
      }
    }
    __syncthreads();

    // ---------- S = q k^T, both heads; cols b = tx and 64+tx (tx<8) ----------
    float s0[9][2], s1[9][2];
    #pragma unroll
    for (int rr = 0; rr < 9; ++rr) { s0[rr][0]=0.f; s0[rr][1]=0.f; s1[rr][0]=0.f; s1[rr][1]=0.f; }
    #pragma unroll
    for (int hh = 0; hh < 2; ++hh) {
      const int off = hh * HD;
      #pragma unroll 2   // cap: full unroll hoists 64 LDS reads + 36 acc -> spill
      for (int kk0 = 0; kk0 < HD; kk0 += 4) {
        float kva[4], kvb[4];
        #pragma unroll
        for (int j = 0; j < 4; ++j) {
          kva[j] = k2T[(off + kk0 + j) * 73 + tx];
          kvb[j] = k2T[(off + kk0 + j) * 73 + 64 + tx];  // junk for tx>=8 (discarded, in-LDS)
        }
        #pragma unroll
        for (int rr = 0; rr < 9; ++rr) {
          float4 q4 = *(const float4*)(q2 + (rr * 8 + ty) * 64 + off + kk0);  // wave-broadcast
          float da = q4.x*kva[0] + q4.y*kva[1] + q4.z*kva[2] + q4.w*kva[3];
          float db = q4.x*kvb[0] + q4.y*kvb[1] + q4.z*kvb[2] + q4.w*kvb[3];
          if (hh == 0) { s0[rr][0] += da; s0[rr][1] += db; }
          else         { s1[rr][0] += da; s1[rr][1] += db; }
        }
      }
    }

    // ---------- bias + mask + softmax (row lives in one wave -> shfl reduce) ----------
    float* S0 = un;
    float* S1 = un + S1_REL;
    #pragma unroll
    for (int rr = 0; rr < 9; ++rr) {
      const int a = rr * 8 + ty;
      const float m0  = maskw[a * NWIN + tx];
      const float m1v = (tx < 8) ? maskw[a * NWIN + 64 + tx] : 0.f;
      #pragma unroll
      for (int hh = 0; hh < 2; ++hh) {
        const int h = h0 + hh;
        float v0 = (hh ? s1[rr][0] : s0[rr][0]) + bias_val(btab, a, tx, h, w31, tlat) + m0;
        float v1 = -1e30f;
        if (tx < 8)
          v1 = (hh ? s1[rr][1] : s0[rr][1]) + bias_val(btab, a, 64 + tx, h, w31, tlat) + m1v;
        float mx = fmaxf(v0, v1);
        #pragma unroll
        for (int o = 32; o > 0; o >>= 1) mx = fmaxf(mx, __shfl_xor(mx, o));
        float e0 = __expf(v0 - mx);
        float e1 = (tx < 8) ? __expf(v1 - mx) : 0.f;
        float sm = e0 + e1;
        #pragma unroll
        for (int o = 32; o > 0; o >>= 1) sm += __shfl_xor(sm, o);
        float inv = 1.0f / sm;
        float* Sh = hh ? S1 : S0;
        Sh[a * S_STRIDE + tx] = e0 * inv;
        if (tx < 8) Sh[a * S_STRIDE + 64 + tx] = e1 * inv;
      }
    }

    // ---------- PV: out col = pass*64 + tx (head = tx/32). Same-wave S dep: no barrier ----------
    {
      const float* Sh = (tx < 32) ? S0 : S1;
      float o[9];
      #pragma unroll
      for (int rr = 0; rr < 9; ++rr) o[rr] = 0.f;
      #pragma unroll 2
      for (int b0 = 0; b0 < NWIN; b0 += 4) {
        float vv[4];
        #pragma unroll
        for (int j = 0; j < 4; ++j) vv[j] = v2[(b0 + j) * 64 + tx];
        #pragma unroll
        for (int rr = 0; rr < 9; ++rr) {
          float4 p4 = *(const float4*)(Sh + (rr * 8 + ty) * S_STRIDE + b0);
          o[rr] += p4.x*vv[0] + p4.y*vv[1] + p4.z*vv[2] + p4.w*vv[3];
        }
      }
      #pragma unroll
      for (int rr = 0; rr < 9; ++rr)
        po[(rr * 8 + ty) * DIM + pass * 64 + tx] = o[rr];
    }
  }  // pass

  // ---------- out projection: y = po @ w_out + b_out ----------
  float c0[9], c1[9], c2[9];
  #pragma unroll
  for (int rr = 0; rr < 9; ++rr) { c0[rr] = 0.f; c1[rr] = 0.f; c2[rr] = 0.f; }
  for (int k0 = 0; k0 < DIM; k0 += 32) {
    __syncthreads();  // protect union (last used as S by PV)
    #pragma unroll
    for (int i = 0; i < 3; ++i) {
      int e4 = tid + i * NT;            // 0..1535
      int kk = e4 / 48;
      int c4 = e4 - kk * 48;
      float4 t = *(const float4*)(wout + (size_t)(k0 + kk) * DIM + c4 * 4);
      *(float4*)(un + kk * 192 + c4 * 4) = t;
    }
    __syncthreads();
    #pragma unroll 2   // cap: see GEMM A
    for (int kk0 = 0; kk0 < 32; kk0 += 4) {
      float wv0[4], wv1[4], wv2[4];
      #pragma unroll
      for (int j = 0; j < 4; ++j) {
        wv0[j] = un[(kk0 + j) * 192 + tx];
        wv1[j] = un[(kk0 + j) * 192 + 64 + tx];
        wv2[j] = un[(kk0 + j) * 192 + 128 + tx];
      }
      #pragma unroll
      for (int rr = 0; rr < 9; ++rr) {
        float4 pa = *(const float4*)(po + (rr * 8 + ty) * DIM + k0 + kk0);  // wave-broadcast
        c0[rr] = fmaf(pa.x, wv0[0], c0[rr]);
        c0[rr] = fmaf(pa.y, wv0[1], c0[rr]);
        c0[rr] = fmaf(pa.z, wv0[2], c0[rr]);
        c0[rr] = fmaf(pa.w, wv0[3], c0[rr]);
        c1[rr] = fmaf(pa.x, wv1[0], c1[rr]);
        c1[rr] = fmaf(pa.y, wv1[1], c1[rr]);
        c1[rr] = fmaf(pa.z, wv1[2], c1[rr]);
        c1[rr] = fmaf(pa.w, wv1[3], c1[rr]);
        c2[rr] = fmaf(pa.x, wv2[0], c2[rr]);
        c2[rr] = fmaf(pa.y, wv2[1], c2[rr]);
        c2[rr] = fmaf(pa.z, wv2[2], c2[rr]);
        c2[rr] = fmaf(pa.w, wv2[3], c2[rr]);
      }
    }
  }
  {
    const float b0v = bout[tx];
    const float b1v = bout[64 + tx];
    const float b2v = bout[128 + tx];
    float* ow = out + (size_t)w * (NWIN * DIM);
    #pragma unroll
    for (int rr = 0; rr < 9; ++rr) {
      int r = rr * 8 + ty;
      ow[r * DIM + tx]       = c0[rr] + b0v;
      ow[r * DIM + 64 + tx]  = c1[rr] + b1v;
      ow[r * DIM + 128 + tx] = c2[rr] + b2v;
    }
  }
}

extern "C" void kernel_launch(void* const* d_in, const int* in_sizes, int n_in,
                              void* d_out, int out_size, void* d_ws, size_t ws_size,
                              hipStream_t stream) {
  const float* x    = (const float*)d_in[0];
  const float* mask = (const float*)d_in[1];
  const float* wqkv = (const float*)d_in[2];
  const float* bqkv = (const float*)d_in[3];
  const float* wout = (const float*)d_in[4];
  const float* bout = (const float*)d_in[5];
  const float* btab = (const float*)d_in[6];
  float* out = (float*)d_out;

  const int nwindows = in_sizes[0] / (NWIN * DIM);   // 1860
  const size_t ldsB = (size_t)LDS_FLOATS * sizeof(float);  // 154,624 B

  (void)hipFuncSetAttribute((const void*)earth_attn_kernel,
                            hipFuncAttributeMaxDynamicSharedMemorySize, (int)ldsB);

  hipLaunchKernelGGL(earth_attn_kernel, dim3(nwindows), dim3(NT), ldsB, stream,
                     x, mask, wqkv, bqkv, wout, bout, btab, out);
}

// Round 5
// 770.701 us; speedup vs baseline: 12.0656x; 2.1297x over previous
//
#include <hip/hip_runtime.h>
#include <cstddef>

typedef short bf16x8 __attribute__((ext_vector_type(8)));   // 8 bf16 in 4 VGPRs (per guide §3)
typedef float f32x4  __attribute__((ext_vector_type(4)));

namespace {
constexpr float QSCALE = 0.17677669529663687f;  // 32^-0.5, folded into wq/bq at prep

// ---- workspace layout (bytes) ----
constexpr size_t BQKV_OFF = 0;                        // ushort[576][384]  B_T for qkv, [wh|wl] split
constexpr size_t WOUT_OFF = 576 * 384 * 2;            // ushort[192][384]  B_T for wout
constexpr size_t BQG_OFF  = WOUT_OFF + 192 * 384 * 2; // float[576] head-grouped qkv bias
constexpr size_t WS_BYTES = BQG_OFF + 576 * 4;        // 592,128 B total

// ---- kernel A LDS layout (half/ushort indices) ----
constexpr int AXS  = 392;                  // A row stride (384 + 8 pad) -> 196 words, %32=4: 2-way free
constexpr int AX_H = 0;                    // [72][392] x split (xh k0-191 | xl k192-383)
constexpr int Q2_H = 72 * AXS;             // 28224: [2][72][40] q bf16 (A-operand)
constexpr int K2_H = Q2_H + 2 * 72 * 40;   // 33984: [2][72][40] k bf16 (B_T operand)
constexpr int V2_H = K2_H + 2 * 72 * 40;   // 39744: [2][32][104] v^T bf16 (B_T operand, tokens padded 96)
constexpr int PB_H = V2_H + 2 * 32 * 104;  // 46400: [8 waves][16][104] P bf16 (A-operand, wave-private)
constexpr int RM_H = PB_H + 8 * 16 * 104;  // 59712: ushort[5184] bias row map for this w31
constexpr int HALF_TOT = RM_H + 5184;      // 64896 halfs
constexpr int BT_F = HALF_TOT / 2;         // float index 32448: float[828*6] bias table slice (tlat)
constexpr int LDSA_BYTES = HALF_TOT * 2 + 828 * 6 * 4;  // 149,664 B < 160 KiB
}

__device__ __forceinline__ unsigned short f2bf(float f) {
  unsigned int u = __builtin_bit_cast(unsigned int, f);
  return (unsigned short)((u + 0x7FFFu + ((u >> 16) & 1u)) >> 16);   // RNE
}
__device__ __forceinline__ float bf2f(unsigned short h) {
  unsigned int u = ((unsigned int)h) << 16;
  return __builtin_bit_cast(float, u);
}
__device__ __forceinline__ int moffv(int i) { return (i < 4) ? i * 16 : 56; }  // m-tiles {0,16,32,48,56}: no OOB rows

// ---------------- prep: weights -> split-bf16 B_T layouts in ws ----------------
__global__ __launch_bounds__(256)
void prep_kernel(const float* __restrict__ wqkv, const float* __restrict__ bqkv,
                 const float* __restrict__ wout, unsigned char* __restrict__ ws) {
  int t = blockIdx.x * 256 + threadIdx.x;
  unsigned short* Bq = (unsigned short*)(ws + BQKV_OFF);
  unsigned short* Bo = (unsigned short*)(ws + WOUT_OFF);
  float* bqg = (float*)(ws + BQG_OFF);
  if (t < 576 * 384) {
    // B_T[n][k]: n head-grouped (h*96 + kind*32 + d), k = [wh 0-191 | wl 192-383]
    int n = t / 384, kk = t % 384;
    int ksrc = kk % 192, part = kk / 192;
    int h = n / 96, r96 = n % 96, kind = r96 / 32, d = r96 % 32;
    float w = wqkv[(size_t)ksrc * 576 + kind * 192 + h * 32 + d];
    if (kind == 0) w *= QSCALE;
    unsigned short hi = f2bf(w);
    Bq[t] = part ? f2bf(w - bf2f(hi)) : hi;
  } else if (t < 576 * 384 + 192 * 384) {
    int t2 = t - 576 * 384;
    int n = t2 / 384, kk = t2 % 384, ksrc = kk % 192, part = kk / 192;
    float w = wout[(size_t)ksrc * 192 + n];
    unsigned short hi = f2bf(w);
    Bo[t2] = part ? f2bf(w - bf2f(hi)) : hi;
  } else if (t < 576 * 384 + 192 * 384 + 576) {
    int n = t - (576 * 384 + 192 * 384);
    int h = n / 96, r96 = n % 96, kind = r96 / 32, d = r96 % 32;
    float b = bqkv[kind * 192 + h * 32 + d];
    if (kind == 0) b *= QSCALE;
    bqg[n] = b;
  }
}

// Split-GEMM tile job: NM m-tiles (16 rows each) x one 16-col n-tile, K=192 split into
// 3 term-regions (xh*wh, xh*wl, xl*wh) of 6 K=32 MFMA steps each.
template<int NM>
__device__ __forceinline__ void gemm_tiles(const unsigned short* __restrict__ abase_lds,
                                           const unsigned short* __restrict__ bptr,
                                           int m0idx, int lanen, int quad, f32x4* acc) {
  #pragma unroll
  for (int i = 0; i < NM; ++i) acc[i] = (f32x4){0.f, 0.f, 0.f, 0.f};
  #pragma unroll 1
  for (int reg = 0; reg < 3; ++reg) {
    const int ab = (reg == 2) ? 192 : 0;
    const int bb = (reg == 1) ? 192 : 0;
    #pragma unroll 2   // cap unroll: keep live set < 128 VGPR (round-4 lesson)
    for (int s = 0; s < 6; ++s) {
      bf16x8 bfr = *(const bf16x8*)(bptr + bb + 32 * s);
      #pragma unroll
      for (int mi = 0; mi < NM; ++mi) {
        int mo = moffv(m0idx + mi);
        bf16x8 afr = *(const bf16x8*)(abase_lds + (mo + lanen) * AXS + ab + 32 * s + quad * 8);
        acc[mi] = __builtin_amdgcn_mfma_f32_16x16x32_bf16(afr, bfr, acc[mi], 0, 0, 0);
      }
    }
  }
}

// ---------------- kernel A: QKV + attention, po -> d_out (scratch) ----------------
__global__ __launch_bounds__(512)
void attn_kernel(const float* __restrict__ x, const float* __restrict__ mask,
                 const float* __restrict__ btab, const unsigned char* __restrict__ ws,
                 float* __restrict__ out) {
  extern __shared__ unsigned short sm[];
  float* btabs = ((float*)sm) + BT_F;
  unsigned short* rm = sm + RM_H;

  const int w = blockIdx.x, tid = threadIdx.x;
  const int lane = tid & 63, ty = tid >> 6;
  const int lanen = lane & 15, quad = lane >> 4;
  const int mrow = w % 30, tlat = w % 31, w31 = w / 31;
  const float* xw = x + (size_t)w * (72 * 192);
  const float* maskw = mask + (size_t)mrow * (72 * 72);
  const unsigned short* Bq = (const unsigned short*)(ws + BQKV_OFF);
  const float* bqg = (const float*)(ws + BQG_OFF);

  // ---- phase 1: stage x split, rowmap, bias slice; zero v^T/P pads ----
  for (int i = tid; i < 3456; i += 512) {             // 72*192/4 float4 jobs
    int r = i / 48, c4 = i % 48;
    float4 v = *(const float4*)(xw + r * 192 + c4 * 4);
    unsigned short h0 = f2bf(v.x), h1 = f2bf(v.y), h2 = f2bf(v.z), h3 = f2bf(v.w);
    ushort4 hv; hv.x = h0; hv.y = h1; hv.z = h2; hv.w = h3;
    ushort4 lv;
    lv.x = f2bf(v.x - bf2f(h0)); lv.y = f2bf(v.y - bf2f(h1));
    lv.z = f2bf(v.z - bf2f(h2)); lv.w = f2bf(v.w - bf2f(h3));
    *(ushort4*)(sm + AX_H + r * AXS + c4 * 4) = hv;
    *(ushort4*)(sm + AX_H + r * AXS + 192 + c4 * 4) = lv;
  }
  for (int i = tid; i < 5184; i += 512) {             // bias row map for this w31
    int P = (i * 60 + w31) % 5184;
    int p1 = P / 72, p2 = P % 72;
    int i1 = p1 / 12, j1 = p1 % 12, i2 = p2 / 12, j2 = p2 % 12;
    rm[i] = (unsigned short)((i1 + 6 * i2) * 23 + j1 - j2 + 11);
  }
  for (int i = tid; i < 4968; i += 512)               // btab[:, tlat, :] slice
    btabs[i] = btab[(size_t)(i / 6) * 186 + tlat * 6 + (i % 6)];
  for (int i = tid; i < 9984; i += 512)               // zero v^T + P buffers (pads persist as 0)
    ((unsigned int*)(sm + V2_H))[i] = 0u;
  __syncthreads();

  #pragma unroll 1
  for (int p = 0; p < 3; ++p) {
    const int nbase = 192 * p;

    // ---- phase 2: QKV MFMA for heads 2p,2p+1 (24 jobs: 12 n-tiles x 2 m-groups) ----
    #pragma unroll 1
    for (int i = 0; i < 3; ++i) {
      int jj = ty + 8 * i;                  // 0..23
      int nt = jj % 12, mg = jj / 12;       // mg0: m-tiles {0,1,2}, mg1: {3,4}
      const unsigned short* bptr = Bq + (size_t)(nbase + nt * 16 + lanen) * 384 + quad * 8;
      f32x4 acc[3];
      if (mg == 0) gemm_tiles<3>(sm + AX_H, bptr, 0, lanen, quad, acc);
      else         gemm_tiles<2>(sm + AX_H, bptr, 3, lanen, quad, acc);
      float bias = bqg[nbase + nt * 16 + lanen];
      int hh = (nt >= 6), w96 = (nt % 6) * 16;
      int nm = mg ? 2 : 3, m0 = mg ? 3 : 0;
      #pragma unroll
      for (int mi = 0; mi < 3; ++mi) {
        if (mi >= nm) break;
        int mo = moffv(m0 + mi);
        if (w96 < 64) {                     // q or k: row-major [72][40]
          unsigned short* dst = sm + ((w96 < 32) ? Q2_H : K2_H) + hh * 2880;
          int d = (w96 < 32) ? (w96 + lanen) : (w96 - 32 + lanen);
          #pragma unroll
          for (int r = 0; r < 4; ++r)
            dst[(mo + quad * 4 + r) * 40 + d] = f2bf(acc[mi][r] + bias);
        } else {                            // v: transposed [32][104] -> 4 consecutive tokens pack
          int d = w96 - 64 + lanen;
          ushort4 hv;
          hv.x = f2bf(acc[mi][0] + bias); hv.y = f2bf(acc[mi][1] + bias);
          hv.z = f2bf(acc[mi][2] + bias); hv.w = f2bf(acc[mi][3] + bias);
          *(ushort4*)(sm + V2_H + hh * 3328 + d * 104 + mo + quad * 4) = hv;
        }
      }
    }
    __syncthreads();

    // ---- phase 3: attention m-strips (10 jobs: 2 heads x 5 strips) ----
    #pragma unroll 1
    for (int j = ty; j < 10; j += 8) {
      int hh = j / 5, mo = moffv(j % 5);
      const unsigned short* q2 = sm + Q2_H + hh * 2880;
      const unsigned short* k2 = sm + K2_H + hh * 2880;
      const unsigned short* v2 = sm + V2_H + hh * 3328;
      unsigned short* pb = sm + PB_H + ty * 1664;   // wave-private [16][104]

      // S = q k^T: 1 A-frag, 5 col-tiles {0,16,32,48,64} (tail cols 72-79 masked below)
      bf16x8 afr = *(const bf16x8*)(q2 + (mo + lanen) * 40 + quad * 8);
      f32x4 s[5];
      #pragma unroll
      for (int t = 0; t < 5; ++t) {
        int no = (t < 4) ? t * 16 : 64;
        bf16x8 bfr = *(const bf16x8*)(k2 + (no + lanen) * 40 + quad * 8);
        s[t] = (f32x4){0.f, 0.f, 0.f, 0.f};
        s[t] = __builtin_amdgcn_mfma_f32_16x16x32_bf16(afr, bfr, s[t], 0, 0, 0);
      }
      // bias + mask + softmax in C-layout registers (row = 16-lane group, shfl reduce)
      int h = 2 * p + hh;
      float lg[5][4];
      #pragma unroll
      for (int t = 0; t < 5; ++t) {
        int ct = ((t < 4) ? t * 16 : 64) + lanen;
        #pragma unroll
        for (int r = 0; r < 4; ++r) {
          if (ct < 72) {
            int m = mo + quad * 4 + r;
            float bv = btabs[(int)rm[m * 72 + ct] * 6 + h];
            lg[t][r] = s[t][r] + bv + maskw[m * 72 + ct];
          } else lg[t][r] = -1e30f;         // kill tail garbage (incl. NaN)
        }
      }
      #pragma unroll
      for (int r = 0; r < 4; ++r) {
        float mx = fmaxf(fmaxf(fmaxf(lg[0][r], lg[1][r]), fmaxf(lg[2][r], lg[3][r])), lg[4][r]);
        #pragma unroll
        for (int o = 8; o > 0; o >>= 1) mx = fmaxf(mx, __shfl_xor(mx, o));
        float sum = 0.f;
        #pragma unroll
        for (int t = 0; t < 5; ++t) { lg[t][r] = __expf(lg[t][r] - mx); sum += lg[t][r]; }
        #pragma unroll
        for (int o = 8; o > 0; o >>= 1) sum += __shfl_xor(sum, o);
        float inv = 1.0f / sum;
        #pragma unroll
        for (int t = 0; t < 5; ++t) {
          int ct = ((t < 4) ? t * 16 : 64) + lanen;
          if (ct < 72) pb[(quad * 4 + r) * 104 + ct] = f2bf(lg[t][r] * inv);
        }
      }
      // O = P V  (P cols 72-95 are persistent zeros; v^T tokens 72-95 zeros)
      f32x4 o2[2];
      o2[0] = (f32x4){0.f, 0.f, 0.f, 0.f}; o2[1] = (f32x4){0.f, 0.f, 0.f, 0.f};
      #pragma unroll
      for (int ks = 0; ks < 3; ++ks) {
        bf16x8 pfr = *(const bf16x8*)(pb + lanen * 104 + ks * 32 + quad * 8);
        #pragma unroll
        for (int n2 = 0; n2 < 2; ++n2) {
          bf16x8 vfr = *(const bf16x8*)(v2 + (n2 * 16 + lanen) * 104 + ks * 32 + quad * 8);
          o2[n2] = __builtin_amdgcn_mfma_f32_16x16x32_bf16(pfr, vfr, o2[n2], 0, 0, 0);
        }
      }
      #pragma unroll
      for (int n2 = 0; n2 < 2; ++n2) {
        int col = h * 32 + n2 * 16 + lanen;
        #pragma unroll
        for (int r = 0; r < 4; ++r)
          out[((size_t)w * 72 + mo + quad * 4 + r) * 192 + col] = o2[n2][r];
      }
    }
    __syncthreads();
  }
}

// ---------------- kernel B: out = po @ w_out + b_out (in-place on d_out) ----------------
__global__ __launch_bounds__(256)
void outproj_kernel(const unsigned char* __restrict__ ws, const float* __restrict__ bout,
                    float* __restrict__ out) {
  __shared__ unsigned short Ax[72 * AXS];   // 56,448 B static -> compiler sees it, 2 blocks/CU
  const int w = blockIdx.x, tid = threadIdx.x;
  const int lane = tid & 63, ty = tid >> 6;
  const int lanen = lane & 15, quad = lane >> 4;
  const unsigned short* Bo = (const unsigned short*)(ws + WOUT_OFF);
  float* rows = out + (size_t)w * (72 * 192);

  for (int i = tid; i < 3456; i += 256) {   // stage po split into LDS (then safe to overwrite)
    int r = i / 48, c4 = i % 48;
    float4 v = *(const float4*)(rows + r * 192 + c4 * 4);
    unsigned short h0 = f2bf(v.x), h1 = f2bf(v.y), h2 = f2bf(v.z), h3 = f2bf(v.w);
    ushort4 hv; hv.x = h0; hv.y = h1; hv.z = h2; hv.w = h3;
    ushort4 lv;
    lv.x = f2bf(v.x - bf2f(h0)); lv.y = f2bf(v.y - bf2f(h1));
    lv.z = f2bf(v.z - bf2f(h2)); lv.w = f2bf(v.w - bf2f(h3));
    *(ushort4*)(Ax + r * AXS + c4 * 4) = hv;
    *(ushort4*)(Ax + r * AXS + 192 + c4 * 4) = lv;
  }
  __syncthreads();

  #pragma unroll 1
  for (int nt = ty; nt < 12; nt += 4) {
    const unsigned short* bptr = Bo + (size_t)(nt * 16 + lanen) * 384 + quad * 8;
    f32x4 acc[5];
    gemm_tiles<5>(Ax, bptr, 0, lanen, quad, acc);
    float bias = bout[nt * 16 + lanen];
    #pragma unroll
    for (int mi = 0; mi < 5; ++mi) {
      int mo = moffv(mi);
      #pragma unroll
      for (int r = 0; r < 4; ++r)
        rows[(mo + quad * 4 + r) * 192 + nt * 16 + lanen] = acc[mi][r] + bias;
    }
  }
}

extern "C" void kernel_launch(void* const* d_in, const int* in_sizes, int n_in,
                              void* d_out, int out_size, void* d_ws, size_t ws_size,
                              hipStream_t stream) {
  const float* x    = (const float*)d_in[0];
  const float* mask = (const float*)d_in[1];
  const float* wqkv = (const float*)d_in[2];
  const float* bqkv = (const float*)d_in[3];
  const float* wout = (const float*)d_in[4];
  const float* bout = (const float*)d_in[5];
  const float* btab = (const float*)d_in[6];
  float* out = (float*)d_out;
  unsigned char* ws = (unsigned char*)d_ws;
  const int nwindows = in_sizes[0] / (72 * 192);   // 1860
  // needs ws_size >= 592,128 B (weight tables); typical harness scratch is far larger.

  prep_kernel<<<dim3(1155), dim3(256), 0, stream>>>(wqkv, bqkv, wout, ws);

  (void)hipFuncSetAttribute((const void*)attn_kernel,
                            hipFuncAttributeMaxDynamicSharedMemorySize, LDSA_BYTES);
  attn_kernel<<<dim3(nwindows), dim3(512), LDSA_BYTES, stream>>>(x, mask, btab, ws, out);

  outproj_kernel<<<dim3(nwindows), dim3(256), 0, stream>>>(ws, bout, out);
}